// Round 9
// baseline (755.912 us; speedup 1.0000x reference)
//
#include <hip/hip_runtime.h>
#include <hip/hip_fp16.h>

#define N_NODES 50000
#define N_EDGES 3200000
#define N_GRAPHS 50
#define IN_F 5
#define HID 64
#define OUT_F 2

#define BKT_SHIFT 5
#define BKT_W 32                       // nodes per bucket
#define NBKT 1563                      // ceil(50000/32)
#define CAP 2560                       // max edges per bucket (mean 2047, sigma 45 -> 11 sigma)
#define TILE_SHIFT 12                  // src tile = src>>12 (0..12)
#define NBIN (BKT_W * 16)              // 512 sort bins
#define NWAVE 8192                     // k_h2g waves (2048 blocks, all co-resident)
#define EPC 6250                       // edges per k_cnt block (512*6250 = 3.2M exact)

// ---------- count edges per bucket ----------
__global__ void k_cnt(const int* dst, int* total) {
    __shared__ int hist[NBKT];
    int t = threadIdx.x, blk = blockIdx.x;
    for (int b = t; b < NBKT; b += 256) hist[b] = 0;
    __syncthreads();
    int base = blk * EPC;
    for (int k = t; k < EPC; k += 256)
        atomicAdd(&hist[dst[base + k] >> BKT_SHIFT], 1);
    __syncthreads();
    for (int b = t; b < NBKT; b += 256) {
        int h = hist[b];
        if (h) atomicAdd(&total[b], h);
    }
}

// ---------- exclusive scan of 1563 bucket totals -> rpB, cursor ----------
__global__ void k_scan(const int* total, int* rpB, int* cursor) {
    __shared__ int s[256];
    int t = threadIdx.x;
    int v[7], sum = 0;
#pragma unroll
    for (int j = 0; j < 7; ++j) {
        int idx = t * 7 + j;
        v[j] = (idx < NBKT) ? total[idx] : 0;
        sum += v[j];
    }
    s[t] = sum;
    __syncthreads();
    for (int off = 1; off < 256; off <<= 1) {
        int a = (t >= off) ? s[t - off] : 0;
        __syncthreads();
        s[t] += a;
        __syncthreads();
    }
    int run = s[t] - sum;
#pragma unroll
    for (int j = 0; j < 7; ++j) {
        int idx = t * 7 + j;
        if (idx < NBKT) { rpB[idx] = run; cursor[idx] = run; }
        run += v[j];
    }
    if (t == 0) rpB[NBKT] = N_EDGES;
}

// ---------- scatter edges to bucket segments via global cursors ----------
__global__ void k_fill(const int* src, const int* dst, const float* ew,
                       int* cursor, int2* bkt) {
    int e = blockIdx.x * 256 + threadIdx.x;      // grid covers 3.2M exactly
    int d = dst[e];
    int b = d >> BKT_SHIFT;
    int slot = atomicAdd(&cursor[b], 1);
    bkt[slot] = make_int2(src[e] | ((d & (BKT_W - 1)) << 16), __float_as_int(ew[e]));
}

// ---------- 512-bin sort by (dst_local, src_tile); in-place 4B compaction ----------
// Output: packed int stream {u16 src | fp16 w} at int-index [rp2[node], rp2e[node])
__global__ void k_bsort(const int* rpB, int2* bkt, int* rp2, int* rp2e, float* dinv) {
    __shared__ int2 ebuf[CAP];          // 20 KB
    __shared__ int hist[NBIN];          // 2 KB
    __shared__ int binoff[NBIN];        // 2 KB (excl offsets, then cursors)
    __shared__ int s[256];
    __shared__ float wd[BKT_W];
    int t = threadIdx.x, b = blockIdx.x;
    int e0 = rpB[b], cnt = rpB[b + 1] - e0;
    for (int i = t; i < NBIN; i += 256) hist[i] = 0;
    if (t < BKT_W) wd[t] = 0.f;
    __syncthreads();
    for (int k = t; k < cnt; k += 256) {
        int2 e = bkt[e0 + k];
        ebuf[k] = e;
        int dl = (e.x >> 16) & (BKT_W - 1);
        int bin = (dl << 4) | ((e.x & 0xFFFF) >> TILE_SHIFT);
        atomicAdd(&hist[bin], 1);
        atomicAdd(&wd[dl], __int_as_float(e.y));
    }
    __syncthreads();
    int h0 = hist[2 * t], h1 = hist[2 * t + 1];
    int pv = h0 + h1;
    s[t] = pv;
    __syncthreads();
    for (int off = 1; off < 256; off <<= 1) {
        int a = (t >= off) ? s[t - off] : 0;
        __syncthreads();
        s[t] += a;
        __syncthreads();
    }
    int pe = s[t] - pv;                 // exclusive over pairs
    binoff[2 * t] = pe;
    binoff[2 * t + 1] = pe + h0;
    __syncthreads();
    if (t < BKT_W) {
        int node = (b << BKT_SHIFT) + t;
        if (node < N_NODES) {
            int startl = binoff[t << 4];
            int endl = (t == BKT_W - 1) ? cnt : binoff[(t + 1) << 4];
            rp2[node]  = 2 * e0 + startl;
            rp2e[node] = 2 * e0 + endl;
            dinv[node] = rsqrtf(1.0f + wd[t]);
        }
    }
    __syncthreads();                     // rp2/rp2e read binoff before cursors mutate
    for (int k = t; k < cnt; k += 256) {
        int2 e = ebuf[k];
        int dl = (e.x >> 16) & (BKT_W - 1);
        int bin = (dl << 4) | ((e.x & 0xFFFF) >> TILE_SHIFT);
        int pos = atomicAdd(&binoff[bin], 1);
        unsigned short wh = __half_as_ushort(__float2half(__int_as_float(e.y)));
        ((int*)bkt)[2 * e0 + pos] = (e.x & 0xFFFF) | ((int)wh << 16);
    }
}

// ---------- xp[i][0..7] = fp16(x[i][f] * dinv[i]) (800KB, L2-resident) ----------
__global__ void k_xprep(const float* x, const float* dinv, __half* xp) {
    int i = blockIdx.x * 256 + threadIdx.x;
    if (i < N_NODES) {
        float di = dinv[i];
        const float* xi = &x[i * IN_F];
        __half* o = &xp[i * 8];
#pragma unroll
        for (int f = 0; f < IN_F; ++f) o[f] = __float2half(xi[f] * di);
        o[5] = o[6] = o[7] = __float2half(0.f);
    }
}

// ---------- layer-1 gather: p = di*(sum w*xp[s] + xp[node]) ----------
__global__ void k_p(const int* rp2, const int* rp2e, const int* pk,
                    const __half* xp, const float* dinv, float* p) {
    int node = blockIdx.x * 4 + (threadIdx.x >> 6);
    int lane = threadIdx.x & 63;
    if (node >= N_NODES) return;
    int b = rp2[node], en = rp2e[node];
    float a0 = 0.f, a1 = 0.f, a2 = 0.f, a3 = 0.f, a4 = 0.f;
    for (int k = b + lane; k < en; k += 64) {
        int e = pk[k];
        float w = __half2float(__ushort_as_half((unsigned short)((unsigned)e >> 16)));
        const __half* xs = &xp[(e & 0xFFFF) * 8];
        int4 xv = *reinterpret_cast<const int4*>(xs);
        __half2 p01 = *(__half2*)&xv.x;
        __half2 p23 = *(__half2*)&xv.y;
        __half2 p45 = *(__half2*)&xv.z;
        a0 += w * __half2float(p01.x); a1 += w * __half2float(p01.y);
        a2 += w * __half2float(p23.x); a3 += w * __half2float(p23.y);
        a4 += w * __half2float(p45.x);
    }
    for (int off = 32; off; off >>= 1) {
        a0 += __shfl_down(a0, off); a1 += __shfl_down(a1, off); a2 += __shfl_down(a2, off);
        a3 += __shfl_down(a3, off); a4 += __shfl_down(a4, off);
    }
    if (lane == 0) {
        float di = dinv[node];
        const __half* xn = &xp[node * 8];
        float* pp = &p[node * IN_F];
        pp[0] = di * (a0 + __half2float(xn[0]));
        pp[1] = di * (a1 + __half2float(xn[1]));
        pp[2] = di * (a2 + __half2float(xn[2]));
        pp[3] = di * (a3 + __half2float(xn[3]));
        pp[4] = di * (a4 + __half2float(xn[4]));
    }
}

// ---------- fused h1 = relu(p@W1+b1); g' = (h1@W2)*dinv quantized int8/row ----------
__global__ void k_h1g(const float* p, const float* W1, const float* b1,
                      const float* W2, const float* dinv,
                      signed char* g8, float* rs) {
    __shared__ float W1s[IN_F * HID];
    __shared__ float W2s[HID * HID];
    __shared__ float b1s[HID];
    int t = threadIdx.x;
    for (int k = t; k < IN_F * HID; k += 256) W1s[k] = W1[k];
    for (int k = t; k < HID * HID; k += 256) W2s[k] = W2[k];
    if (t < HID) b1s[t] = b1[t];
    __syncthreads();
    int lane = t & 63;
    int wid = blockIdx.x * 4 + (t >> 6);
    int nw = gridDim.x * 4;
    for (int node = wid; node < N_NODES; node += nw) {
        const float* pp = &p[node * IN_F];
        float pv0 = pp[0], pv1 = pp[1], pv2 = pp[2], pv3 = pp[3], pv4 = pp[4];
        float h = b1s[lane] + pv0 * W1s[lane] + pv1 * W1s[64 + lane] + pv2 * W1s[128 + lane]
                + pv3 * W1s[192 + lane] + pv4 * W1s[256 + lane];
        h = fmaxf(h, 0.f);
        float acc = 0.f;
#pragma unroll
        for (int f = 0; f < HID; ++f) {
            float hf = __int_as_float(__builtin_amdgcn_readlane(__float_as_int(h), f));
            acc += hf * W2s[f * HID + lane];
        }
        float gv = acc * dinv[node];                 // g' value
        float am = fabsf(gv);
        for (int off = 32; off; off >>= 1) am = fmaxf(am, __shfl_xor(am, off));
        float inv = (am > 0.f) ? 127.0f / am : 0.f;
        g8[node * HID + lane] = (signed char)__float2int_rn(gv * inv);
        if (lane == 0) rs[node] = (am > 0.f) ? am * (1.0f / 127.0f) : 0.f;
    }
}

// ---------- layer-2 gather (int8 rows, 16-deep) fused with bias/relu/pool ----------
__global__ __launch_bounds__(256, 8) void k_h2g(const int* rp2, const int* rp2e,
                      const int* pk, const float* dinv, const signed char* g8,
                      const float* rs, const float* b2, const int* batch, float* pool) {
    int t = threadIdx.x, lane = t & 63;
    int wid = blockIdx.x * 4 + (t >> 6);
    int n0 = (int)(((long long)wid * N_NODES) / NWAVE);
    int n1 = (int)(((long long)(wid + 1) * N_NODES) / NWAVE);
    if (n0 >= n1) return;
    float bj = b2[lane];
    float accp = 0.f;
    int cur = batch[n0];
    for (int node = n0; node < n1; ++node) {
        int k0 = rp2[node], e1 = rp2e[node];
        float acc = (float)g8[node * HID + lane] * rs[node];   // self-loop
        for (; k0 < e1; k0 += 64) {
            int kk = k0 + lane;
            int ev = (kk < e1) ? pk[kk] : 0;              // pad: src=0, w=+0.0
            int m = e1 - k0; if (m > 64) m = 64;
            int ng = (m + 15) >> 4;
            for (int q = 0; q < ng; ++q) {
                float vv[16], ww[16];
#pragma unroll
                for (int j = 0; j < 16; ++j) {
                    int u = __builtin_amdgcn_readlane(ev, q * 16 + j);
                    int sx = u & 0xFFFF;
                    float w = __half2float(__ushort_as_half((unsigned short)((unsigned)u >> 16)));
                    ww[j] = w * rs[sx];
                    vv[j] = (float)g8[sx * HID + lane];
                }
#pragma unroll
                for (int j = 0; j < 16; ++j) acc += vv[j] * ww[j];
            }
        }
        float h2 = fmaxf(dinv[node] * acc + bj, 0.f);
        int bb = batch[node];
        if (bb != cur) {
            atomicAdd(&pool[cur * HID + lane], accp);
            cur = bb;
            accp = 0.f;
        }
        accp += h2;
    }
    atomicAdd(&pool[cur * HID + lane], accp);
}

__device__ int lowb(const int* a, int n, int v) {
    int lo = 0, hi = n;
    while (lo < hi) { int m = (lo + hi) >> 1; if (a[m] < v) lo = m + 1; else hi = m; }
    return lo;
}

__global__ void k_out(const float* pool, const int* batch, const float* Wo,
                      const float* bo, float* out) {
    int t = blockIdx.x * blockDim.x + threadIdx.x;
    if (t < N_GRAPHS * OUT_F) {
        int gi = t / OUT_F, k = t % OUT_F;
        int c = lowb(batch, N_NODES, gi + 1) - lowb(batch, N_NODES, gi);
        float cf = fmaxf((float)c, 1.0f);
        float acc = bo[k];
        for (int f = 0; f < HID; ++f)
            acc += (pool[gi * HID + f] / cf) * Wo[f * OUT_F + k];
        out[t] = acc;
    }
}

extern "C" void kernel_launch(void* const* d_in, const int* in_sizes, int n_in,
                              void* d_out, int out_size, void* d_ws, size_t ws_size,
                              hipStream_t stream) {
    const float* x   = (const float*)d_in[0];
    const int*   ei  = (const int*)d_in[1];
    const float* ea  = (const float*)d_in[2];
    const int*   bat = (const int*)d_in[3];
    const float* W1  = (const float*)d_in[4];
    const float* b1  = (const float*)d_in[5];
    const float* W2  = (const float*)d_in[6];
    const float* b2  = (const float*)d_in[7];
    const float* Wo  = (const float*)d_in[8];
    const float* bo  = (const float*)d_in[9];
    float* out = (float*)d_out;

    const int* src = ei;
    const int* dst = ei + N_EDGES;

    // workspace layout (float units) — total 7,857,968 floats = 31.4 MB
    float* ws = (float*)d_ws;
    int*   rpB    = (int*)ws;                        // 1564 (pad 1568)
    int*   cursor = (int*)(ws + 1568);               // 1563 (pad 1568)
    int*   rp2    = (int*)(ws + 3136);               // 50000 (pad 50016)
    int*   rp2e   = (int*)(ws + 53152);              // 50000 (pad 50016)
    float* dinv   = ws + 103168;                     // 50000 (pad 50016)
    float* rs     = ws + 153184;                     // 50000 (pad 50016)
    float* pool   = ws + 203200;                     // 3200
    int*   total  = (int*)(ws + 206400);             // 1563 (pad 1568)
    float* p      = ws + 207968;                     // 250000
    int2*  bkt    = (int2*)(ws + 457968);            // 3.2M int2; packed int stream after k_bsort
    signed char* g8 = (signed char*)(ws + 6857968);  // 3.2MB = 800000 floats
    __half* xp    = (__half*)(ws + 7657968);         // 400000 halves = 200000 floats

    hipMemsetAsync(total, 0, NBKT * sizeof(int), stream);
    hipMemsetAsync(pool, 0, N_GRAPHS * HID * sizeof(float), stream);

    k_cnt  <<<512, 256, 0, stream>>>(dst, total);
    k_scan <<<1, 256, 0, stream>>>(total, rpB, cursor);
    k_fill <<<N_EDGES / 256, 256, 0, stream>>>(src, dst, ea, cursor, bkt);
    k_bsort<<<NBKT, 256, 0, stream>>>(rpB, bkt, rp2, rp2e, dinv);
    k_xprep<<<(N_NODES + 255) / 256, 256, 0, stream>>>(x, dinv, xp);
    k_p    <<<(N_NODES + 3) / 4, 256, 0, stream>>>(rp2, rp2e, (const int*)bkt, xp, dinv, p);
    k_h1g  <<<1024, 256, 0, stream>>>(p, W1, b1, W2, dinv, g8, rs);
    k_h2g  <<<NWAVE / 4, 256, 0, stream>>>(rp2, rp2e, (const int*)bkt, dinv, g8, rs, b2, bat, pool);
    k_out  <<<1, 128, 0, stream>>>(pool, bat, Wo, bo, out);
}

// Round 10
// 306.983 us; speedup vs baseline: 2.4624x; 2.4624x over previous
//
#include <hip/hip_runtime.h>
#include <hip/hip_fp16.h>

#define N_NODES 50000
#define N_EDGES 3200000
#define N_GRAPHS 50
#define IN_F 5
#define HID 64
#define OUT_F 2

#define BKT_SHIFT 5
#define BKT_W 32                       // nodes per bucket
#define NBKT 1563                      // ceil(50000/32)
#define NB1 250                        // phase-1 blocks
#define EPB 12800                      // edges per phase-1 block (250*12800 = 3.2M exact)
#define CAP 2560                       // max edges per bucket (mean 2047, sigma 45 -> 11 sigma)
#define TILE_SHIFT 12                  // src tile = src>>12 (0..12)
#define NBIN (BKT_W * 16)              // 512 sort bins
#define NWAVE 8192                     // k_h2g waves (2048 blocks, all co-resident)

// ---------- phase 1a: per-(bucket,block) histogram, LDS-aggregated, 1024 thr ----------
__global__ void k_bhist(const int* dst, unsigned short* cw) {
    __shared__ int hist[NBKT];
    int t = threadIdx.x, blk = blockIdx.x;
    for (int b = t; b < NBKT; b += 1024) hist[b] = 0;
    __syncthreads();
    int base = blk * EPB;
    for (int k = t; k < EPB; k += 1024)
        atomicAdd(&hist[dst[base + k] >> BKT_SHIFT], 1);
    __syncthreads();
    for (int b = t; b < NBKT; b += 1024)
        cw[b * NB1 + blk] = (unsigned short)hist[b];
}

// ---------- phase 1b: per-bucket exclusive scan over the 250 block-counts ----------
__global__ void k_bscanA(unsigned short* cw, int* total) {
    __shared__ int s[256];
    int t = threadIdx.x, b = blockIdx.x;
    int v = (t < NB1) ? (int)cw[b * NB1 + t] : 0;
    s[t] = v;
    __syncthreads();
    for (int off = 1; off < 256; off <<= 1) {
        int a = (t >= off) ? s[t - off] : 0;
        __syncthreads();
        s[t] += a;
        __syncthreads();
    }
    if (t < NB1) cw[b * NB1 + t] = (unsigned short)(s[t] - v);  // in-place exclusive
    if (t == 255) total[b] = s[255];
}

// ---------- phase 1c: exclusive scan of 1563 bucket totals -> rpB ----------
__global__ void k_bscanB(const int* total, int* rpB) {
    __shared__ int s[256];
    int t = threadIdx.x;
    int v[7], sum = 0;
#pragma unroll
    for (int j = 0; j < 7; ++j) {
        int idx = t * 7 + j;
        v[j] = (idx < NBKT) ? total[idx] : 0;
        sum += v[j];
    }
    s[t] = sum;
    __syncthreads();
    for (int off = 1; off < 256; off <<= 1) {
        int a = (t >= off) ? s[t - off] : 0;
        __syncthreads();
        s[t] += a;
        __syncthreads();
    }
    int run = s[t] - sum;
#pragma unroll
    for (int j = 0; j < 7; ++j) {
        int idx = t * 7 + j;
        if (idx < NBKT) rpB[idx] = run;
        run += v[j];
    }
    if (t == 0) rpB[NBKT] = N_EDGES;
}

// ---------- phase 1d: deterministic scatter to bucket segments, 1024 thr ----------
__global__ void k_bucket(const int* src, const int* dst, const float* ew,
                         const unsigned short* cw, const int* rpB, int2* bkt) {
    __shared__ int base[NBKT];
    __shared__ int off[NBKT];
    int t = threadIdx.x, blk = blockIdx.x;
    for (int b = t; b < NBKT; b += 1024) {
        base[b] = (int)cw[b * NB1 + blk] + rpB[b];
        off[b] = 0;
    }
    __syncthreads();
    int ebase = blk * EPB;
    for (int k = t; k < EPB; k += 1024) {
        int idx = ebase + k;
        int d = dst[idx];
        int b = d >> BKT_SHIFT;
        int sl = base[b] + atomicAdd(&off[b], 1);
        bkt[sl] = make_int2(src[idx] | ((d & (BKT_W - 1)) << 16), __float_as_int(ew[idx]));
    }
}

// ---------- phase 2: 512-bin sort by (dst_local, src_tile); in-place 4B compaction ----------
// Output: packed int stream {u16 src | fp16 w} at int-index [rp2[node], rp2e[node])
__global__ void k_bsort(const int* rpB, int2* bkt, int* rp2, int* rp2e, float* dinv) {
    __shared__ int2 ebuf[CAP];          // 20 KB
    __shared__ int hist[NBIN];          // 2 KB
    __shared__ int binoff[NBIN];        // 2 KB (excl offsets, then cursors)
    __shared__ int s[256];
    __shared__ float wd[BKT_W];
    int t = threadIdx.x, b = blockIdx.x;
    int e0 = rpB[b], cnt = rpB[b + 1] - e0;
    for (int i = t; i < NBIN; i += 256) hist[i] = 0;
    if (t < BKT_W) wd[t] = 0.f;
    __syncthreads();
    for (int k = t; k < cnt; k += 256) {
        int2 e = bkt[e0 + k];
        ebuf[k] = e;
        int dl = (e.x >> 16) & (BKT_W - 1);
        int bin = (dl << 4) | ((e.x & 0xFFFF) >> TILE_SHIFT);
        atomicAdd(&hist[bin], 1);
        atomicAdd(&wd[dl], __int_as_float(e.y));
    }
    __syncthreads();
    int h0 = hist[2 * t], h1 = hist[2 * t + 1];
    int pv = h0 + h1;
    s[t] = pv;
    __syncthreads();
    for (int off = 1; off < 256; off <<= 1) {
        int a = (t >= off) ? s[t - off] : 0;
        __syncthreads();
        s[t] += a;
        __syncthreads();
    }
    int pe = s[t] - pv;                 // exclusive over pairs
    binoff[2 * t] = pe;
    binoff[2 * t + 1] = pe + h0;
    __syncthreads();
    if (t < BKT_W) {
        int node = (b << BKT_SHIFT) + t;
        if (node < N_NODES) {
            int startl = binoff[t << 4];
            int endl = (t == BKT_W - 1) ? cnt : binoff[(t + 1) << 4];
            rp2[node]  = 2 * e0 + startl;
            rp2e[node] = 2 * e0 + endl;
            dinv[node] = rsqrtf(1.0f + wd[t]);
        }
    }
    __syncthreads();                     // rp2/rp2e read binoff before cursors mutate
    for (int k = t; k < cnt; k += 256) {
        int2 e = ebuf[k];
        int dl = (e.x >> 16) & (BKT_W - 1);
        int bin = (dl << 4) | ((e.x & 0xFFFF) >> TILE_SHIFT);
        int pos = atomicAdd(&binoff[bin], 1);
        unsigned short wh = __half_as_ushort(__float2half(__int_as_float(e.y)));
        ((int*)bkt)[2 * e0 + pos] = (e.x & 0xFFFF) | ((int)wh << 16);
    }
}

// ---------- xp[i][0..7] = fp16(x[i][f] * dinv[i]) (800KB, L2-resident) ----------
__global__ void k_xprep(const float* x, const float* dinv, __half* xp) {
    int i = blockIdx.x * 256 + threadIdx.x;
    if (i < N_NODES) {
        float di = dinv[i];
        const float* xi = &x[i * IN_F];
        __half* o = &xp[i * 8];
#pragma unroll
        for (int f = 0; f < IN_F; ++f) o[f] = __float2half(xi[f] * di);
        o[5] = o[6] = o[7] = __float2half(0.f);
    }
}

// ---------- layer-1 gather: p = di*(sum w*xp[s] + xp[node]) ----------
__global__ void k_p(const int* rp2, const int* rp2e, const int* pk,
                    const __half* xp, const float* dinv, float* p) {
    int node = blockIdx.x * 4 + (threadIdx.x >> 6);
    int lane = threadIdx.x & 63;
    if (node >= N_NODES) return;
    int b = rp2[node], en = rp2e[node];
    float a0 = 0.f, a1 = 0.f, a2 = 0.f, a3 = 0.f, a4 = 0.f;
    for (int k = b + lane; k < en; k += 64) {
        int e = pk[k];
        float w = __half2float(__ushort_as_half((unsigned short)((unsigned)e >> 16)));
        const __half* xs = &xp[(e & 0xFFFF) * 8];
        int4 xv = *reinterpret_cast<const int4*>(xs);
        __half2 p01 = *(__half2*)&xv.x;
        __half2 p23 = *(__half2*)&xv.y;
        __half2 p45 = *(__half2*)&xv.z;
        a0 += w * __half2float(p01.x); a1 += w * __half2float(p01.y);
        a2 += w * __half2float(p23.x); a3 += w * __half2float(p23.y);
        a4 += w * __half2float(p45.x);
    }
    for (int off = 32; off; off >>= 1) {
        a0 += __shfl_down(a0, off); a1 += __shfl_down(a1, off); a2 += __shfl_down(a2, off);
        a3 += __shfl_down(a3, off); a4 += __shfl_down(a4, off);
    }
    if (lane == 0) {
        float di = dinv[node];
        const __half* xn = &xp[node * 8];
        float* pp = &p[node * IN_F];
        pp[0] = di * (a0 + __half2float(xn[0]));
        pp[1] = di * (a1 + __half2float(xn[1]));
        pp[2] = di * (a2 + __half2float(xn[2]));
        pp[3] = di * (a3 + __half2float(xn[3]));
        pp[4] = di * (a4 + __half2float(xn[4]));
    }
}

// ---------- fused h1 = relu(p@W1+b1); g' = (h1@W2)*dinv quantized int8/row ----------
__global__ void k_h1g(const float* p, const float* W1, const float* b1,
                      const float* W2, const float* dinv,
                      signed char* g8, float* rs) {
    __shared__ float W1s[IN_F * HID];
    __shared__ float W2s[HID * HID];
    __shared__ float b1s[HID];
    int t = threadIdx.x;
    for (int k = t; k < IN_F * HID; k += 256) W1s[k] = W1[k];
    for (int k = t; k < HID * HID; k += 256) W2s[k] = W2[k];
    if (t < HID) b1s[t] = b1[t];
    __syncthreads();
    int lane = t & 63;
    int wid = blockIdx.x * 4 + (t >> 6);
    int nw = gridDim.x * 4;
    for (int node = wid; node < N_NODES; node += nw) {
        const float* pp = &p[node * IN_F];
        float pv0 = pp[0], pv1 = pp[1], pv2 = pp[2], pv3 = pp[3], pv4 = pp[4];
        float h = b1s[lane] + pv0 * W1s[lane] + pv1 * W1s[64 + lane] + pv2 * W1s[128 + lane]
                + pv3 * W1s[192 + lane] + pv4 * W1s[256 + lane];
        h = fmaxf(h, 0.f);
        float acc = 0.f;
#pragma unroll
        for (int f = 0; f < HID; ++f) {
            float hf = __int_as_float(__builtin_amdgcn_readlane(__float_as_int(h), f));
            acc += hf * W2s[f * HID + lane];
        }
        float gv = acc * dinv[node];                 // g' value
        float am = fabsf(gv);
        for (int off = 32; off; off >>= 1) am = fmaxf(am, __shfl_xor(am, off));
        float inv = (am > 0.f) ? 127.0f / am : 0.f;
        g8[node * HID + lane] = (signed char)__float2int_rn(gv * inv);
        if (lane == 0) rs[node] = (am > 0.f) ? am * (1.0f / 127.0f) : 0.f;
    }
}

// ---------- layer-2 gather (int8 rows, 16-deep) fused with bias/relu/pool ----------
__global__ __launch_bounds__(256, 8) void k_h2g(const int* rp2, const int* rp2e,
                      const int* pk, const float* dinv, const signed char* g8,
                      const float* rs, const float* b2, const int* batch, float* pool) {
    int t = threadIdx.x, lane = t & 63;
    int wid = blockIdx.x * 4 + (t >> 6);
    int n0 = (int)(((long long)wid * N_NODES) / NWAVE);
    int n1 = (int)(((long long)(wid + 1) * N_NODES) / NWAVE);
    if (n0 >= n1) return;
    float bj = b2[lane];
    float accp = 0.f;
    int cur = batch[n0];
    for (int node = n0; node < n1; ++node) {
        int k0 = rp2[node], e1 = rp2e[node];
        float acc = (float)g8[node * HID + lane] * rs[node];   // self-loop
        for (; k0 < e1; k0 += 64) {
            int kk = k0 + lane;
            int ev = (kk < e1) ? pk[kk] : 0;              // pad: src=0, w=+0.0
            int m = e1 - k0; if (m > 64) m = 64;
            int ng = (m + 15) >> 4;
            for (int q = 0; q < ng; ++q) {
                float vv[16], ww[16];
#pragma unroll
                for (int j = 0; j < 16; ++j) {
                    int u = __builtin_amdgcn_readlane(ev, q * 16 + j);
                    int sx = u & 0xFFFF;
                    float w = __half2float(__ushort_as_half((unsigned short)((unsigned)u >> 16)));
                    ww[j] = w * rs[sx];
                    vv[j] = (float)g8[sx * HID + lane];
                }
#pragma unroll
                for (int j = 0; j < 16; ++j) acc += vv[j] * ww[j];
            }
        }
        float h2 = fmaxf(dinv[node] * acc + bj, 0.f);
        int bb = batch[node];
        if (bb != cur) {
            atomicAdd(&pool[cur * HID + lane], accp);
            cur = bb;
            accp = 0.f;
        }
        accp += h2;
    }
    atomicAdd(&pool[cur * HID + lane], accp);
}

__device__ int lowb(const int* a, int n, int v) {
    int lo = 0, hi = n;
    while (lo < hi) { int m = (lo + hi) >> 1; if (a[m] < v) lo = m + 1; else hi = m; }
    return lo;
}

__global__ void k_out(const float* pool, const int* batch, const float* Wo,
                      const float* bo, float* out) {
    int t = blockIdx.x * blockDim.x + threadIdx.x;
    if (t < N_GRAPHS * OUT_F) {
        int gi = t / OUT_F, k = t % OUT_F;
        int c = lowb(batch, N_NODES, gi + 1) - lowb(batch, N_NODES, gi);
        float cf = fmaxf((float)c, 1.0f);
        float acc = bo[k];
        for (int f = 0; f < HID; ++f)
            acc += (pool[gi * HID + f] / cf) * Wo[f * OUT_F + k];
        out[t] = acc;
    }
}

extern "C" void kernel_launch(void* const* d_in, const int* in_sizes, int n_in,
                              void* d_out, int out_size, void* d_ws, size_t ws_size,
                              hipStream_t stream) {
    const float* x   = (const float*)d_in[0];
    const int*   ei  = (const int*)d_in[1];
    const float* ea  = (const float*)d_in[2];
    const int*   bat = (const int*)d_in[3];
    const float* W1  = (const float*)d_in[4];
    const float* b1  = (const float*)d_in[5];
    const float* W2  = (const float*)d_in[6];
    const float* b2  = (const float*)d_in[7];
    const float* Wo  = (const float*)d_in[8];
    const float* bo  = (const float*)d_in[9];
    float* out = (float*)d_out;

    const int* src = ei;
    const int* dst = ei + N_EDGES;

    // workspace layout (float units) — total 7,854,832 floats = 31.4 MB
    float* ws = (float*)d_ws;
    int*   rpB   = (int*)ws;                         // 1564 (pad 1568)
    int*   rp2   = (int*)(ws + 1568);                // 50000 (pad 50016)
    int*   rp2e  = (int*)(ws + 51584);               // 50000 (pad 50016)
    float* dinv  = ws + 101600;                      // 50000 (pad 50016)
    float* rs    = ws + 151616;                      // 50000 (pad 50016)
    float* pool  = ws + 201632;                      // 3200
    int*   total = (int*)(ws + 201632);              // 1563, overlays pool, dead after bscanB
    unsigned short* cw = (unsigned short*)(ws + 204832);  // 390750 u16, dead after k_bucket
    float* p     = ws + 204832;                      // 250000, overlays cw, written after
    int2*  bkt   = (int2*)(ws + 454832);             // 3.2M int2; packed int stream after k_bsort
    signed char* g8 = (signed char*)(ws + 6854832);  // 3.2MB = 800000 floats
    __half* xp   = (__half*)(ws + 7654832);          // 400000 halves = 200000 floats

    k_bhist <<<NB1, 1024, 0, stream>>>(dst, cw);
    k_bscanA<<<NBKT, 256, 0, stream>>>(cw, total);
    k_bscanB<<<1, 256, 0, stream>>>(total, rpB);
    hipMemsetAsync(pool, 0, N_GRAPHS * HID * sizeof(float), stream);  // after bscanB (total overlays pool)
    k_bucket<<<NB1, 1024, 0, stream>>>(src, dst, ea, cw, rpB, bkt);
    k_bsort <<<NBKT, 256, 0, stream>>>(rpB, bkt, rp2, rp2e, dinv);
    k_xprep <<<(N_NODES + 255) / 256, 256, 0, stream>>>(x, dinv, xp);
    k_p     <<<(N_NODES + 3) / 4, 256, 0, stream>>>(rp2, rp2e, (const int*)bkt, xp, dinv, p);
    k_h1g   <<<1024, 256, 0, stream>>>(p, W1, b1, W2, dinv, g8, rs);
    k_h2g   <<<NWAVE / 4, 256, 0, stream>>>(rp2, rp2e, (const int*)bkt, dinv, g8, rs, b2, bat, pool);
    k_out   <<<1, 128, 0, stream>>>(pool, bat, Wo, bo, out);
}

// Round 11
// 279.803 us; speedup vs baseline: 2.7016x; 1.0971x over previous
//
#include <hip/hip_runtime.h>
#include <hip/hip_fp16.h>

#define N_NODES 50000
#define N_EDGES 3200000
#define N_GRAPHS 50
#define IN_F 5
#define HID 64
#define OUT_F 2

#define BKT_SHIFT 5
#define BKT_W 32                       // nodes per bucket
#define NBKT 1563                      // ceil(50000/32)
#define NB1 250                        // phase-1 blocks
#define EPB 12800                      // edges per phase-1 block (250*12800 = 3.2M exact)
#define CAP 2560                       // max edges per bucket (mean 2047, sigma 45 -> 11 sigma)
#define TILE_SHIFT 12                  // src tile = src>>12 (0..12)
#define NBIN (BKT_W * 16)              // 512 sort bins
#define NWAVE 8192                     // k_h2g waves (2048 blocks, all co-resident)

// ---------- phase 1a: per-(bucket,block) histogram, LDS-aggregated, 1024 thr ----------
__global__ void k_bhist(const int* dst, unsigned short* cw) {
    __shared__ int hist[NBKT];
    int t = threadIdx.x, blk = blockIdx.x;
    for (int b = t; b < NBKT; b += 1024) hist[b] = 0;
    __syncthreads();
    int base = blk * EPB;
    for (int k = t; k < EPB; k += 1024)
        atomicAdd(&hist[dst[base + k] >> BKT_SHIFT], 1);
    __syncthreads();
    for (int b = t; b < NBKT; b += 1024)
        cw[b * NB1 + blk] = (unsigned short)hist[b];
}

// ---------- phase 1b: per-bucket exclusive scan over the 250 block-counts ----------
__global__ void k_bscanA(unsigned short* cw, int* total) {
    __shared__ int s[256];
    int t = threadIdx.x, b = blockIdx.x;
    int v = (t < NB1) ? (int)cw[b * NB1 + t] : 0;
    s[t] = v;
    __syncthreads();
    for (int off = 1; off < 256; off <<= 1) {
        int a = (t >= off) ? s[t - off] : 0;
        __syncthreads();
        s[t] += a;
        __syncthreads();
    }
    if (t < NB1) cw[b * NB1 + t] = (unsigned short)(s[t] - v);  // in-place exclusive
    if (t == 255) total[b] = s[255];
}

// ---------- phase 1c: exclusive scan of 1563 bucket totals -> rpB ----------
__global__ void k_bscanB(const int* total, int* rpB) {
    __shared__ int s[256];
    int t = threadIdx.x;
    int v[7], sum = 0;
#pragma unroll
    for (int j = 0; j < 7; ++j) {
        int idx = t * 7 + j;
        v[j] = (idx < NBKT) ? total[idx] : 0;
        sum += v[j];
    }
    s[t] = sum;
    __syncthreads();
    for (int off = 1; off < 256; off <<= 1) {
        int a = (t >= off) ? s[t - off] : 0;
        __syncthreads();
        s[t] += a;
        __syncthreads();
    }
    int run = s[t] - sum;
#pragma unroll
    for (int j = 0; j < 7; ++j) {
        int idx = t * 7 + j;
        if (idx < NBKT) rpB[idx] = run;
        run += v[j];
    }
    if (t == 0) rpB[NBKT] = N_EDGES;
}

// ---------- phase 1d: deterministic scatter, 4B payload {src16 | dl5 | wq11}, 1024 thr ----------
__global__ void k_bucket(const int* src, const int* dst, const float* ew,
                         const unsigned short* cw, const int* rpB, int* bkt) {
    __shared__ int base[NBKT];
    __shared__ int off[NBKT];
    int t = threadIdx.x, blk = blockIdx.x;
    for (int b = t; b < NBKT; b += 1024) {
        base[b] = (int)cw[b * NB1 + blk] + rpB[b];
        off[b] = 0;
    }
    __syncthreads();
    int ebase = blk * EPB;
    for (int k = t; k < EPB; k += 1024) {
        int idx = ebase + k;
        int d = dst[idx];
        int b = d >> BKT_SHIFT;
        int sl = base[b] + atomicAdd(&off[b], 1);
        int wq = (int)rintf(ew[idx] * 2047.0f);
        bkt[sl] = src[idx] | ((d & (BKT_W - 1)) << 16) | (wq << 21);
    }
}

// ---------- phase 2: 512-bin sort by (dst_local, src_tile); integer degree; emit {src|fp16 w} ----------
__global__ void k_bsort(const int* rpB, int* bkt, int* rp2, int* rp2e, float* dinv) {
    __shared__ int ebuf[CAP];           // 10 KB
    __shared__ int hist[NBIN];          // 2 KB
    __shared__ int binoff[NBIN];        // 2 KB (excl offsets, then cursors)
    __shared__ int s[256];
    __shared__ int wdI[BKT_W];
    int t = threadIdx.x, b = blockIdx.x;
    int e0 = rpB[b], cnt = rpB[b + 1] - e0;
    for (int i = t; i < NBIN; i += 256) hist[i] = 0;
    if (t < BKT_W) wdI[t] = 0;
    __syncthreads();
    for (int k = t; k < cnt; k += 256) {
        int u = bkt[e0 + k];
        ebuf[k] = u;
        int dl = (u >> 16) & (BKT_W - 1);
        int bin = (dl << 4) | ((u & 0xFFFF) >> TILE_SHIFT);
        atomicAdd(&hist[bin], 1);
        atomicAdd(&wdI[dl], (int)((unsigned)u >> 21));
    }
    __syncthreads();
    int h0 = hist[2 * t], h1 = hist[2 * t + 1];
    int pv = h0 + h1;
    s[t] = pv;
    __syncthreads();
    for (int off = 1; off < 256; off <<= 1) {
        int a = (t >= off) ? s[t - off] : 0;
        __syncthreads();
        s[t] += a;
        __syncthreads();
    }
    int pe = s[t] - pv;                 // exclusive over pairs
    binoff[2 * t] = pe;
    binoff[2 * t + 1] = pe + h0;
    __syncthreads();
    if (t < BKT_W) {
        int node = (b << BKT_SHIFT) + t;
        if (node < N_NODES) {
            int startl = binoff[t << 4];
            int endl = (t == BKT_W - 1) ? cnt : binoff[(t + 1) << 4];
            rp2[node]  = e0 + startl;
            rp2e[node] = e0 + endl;
            dinv[node] = rsqrtf(1.0f + (float)wdI[t] * (1.0f / 2047.0f));
        }
    }
    __syncthreads();                     // rp2/rp2e read binoff before cursors mutate
    for (int k = t; k < cnt; k += 256) {
        int u = ebuf[k];
        int dl = (u >> 16) & (BKT_W - 1);
        int bin = (dl << 4) | ((u & 0xFFFF) >> TILE_SHIFT);
        int pos = atomicAdd(&binoff[bin], 1);
        float wf = (float)((unsigned)u >> 21) * (1.0f / 2047.0f);
        unsigned short wh = __half_as_ushort(__float2half(wf));
        bkt[e0 + pos] = (u & 0xFFFF) | ((int)wh << 16);
    }
}

// ---------- xp[i][0..7] = fp16(x[i][f] * dinv[i]) (800KB, L2-resident) ----------
__global__ void k_xprep(const float* x, const float* dinv, __half* xp) {
    int i = blockIdx.x * 256 + threadIdx.x;
    if (i < N_NODES) {
        float di = dinv[i];
        const float* xi = &x[i * IN_F];
        __half* o = &xp[i * 8];
#pragma unroll
        for (int f = 0; f < IN_F; ++f) o[f] = __float2half(xi[f] * di);
        o[5] = o[6] = o[7] = __float2half(0.f);
    }
}

// ---------- layer-1 gather: p = di*(sum w*xp[s] + xp[node]) ----------
__global__ void k_p(const int* rp2, const int* rp2e, const int* pk,
                    const __half* xp, const float* dinv, float* p) {
    int node = blockIdx.x * 4 + (threadIdx.x >> 6);
    int lane = threadIdx.x & 63;
    if (node >= N_NODES) return;
    int b = rp2[node], en = rp2e[node];
    float a0 = 0.f, a1 = 0.f, a2 = 0.f, a3 = 0.f, a4 = 0.f;
    for (int k = b + lane; k < en; k += 64) {
        int e = pk[k];
        float w = __half2float(__ushort_as_half((unsigned short)((unsigned)e >> 16)));
        const __half* xs = &xp[(e & 0xFFFF) * 8];
        int4 xv = *reinterpret_cast<const int4*>(xs);
        __half2 p01 = *(__half2*)&xv.x;
        __half2 p23 = *(__half2*)&xv.y;
        __half2 p45 = *(__half2*)&xv.z;
        a0 += w * __half2float(p01.x); a1 += w * __half2float(p01.y);
        a2 += w * __half2float(p23.x); a3 += w * __half2float(p23.y);
        a4 += w * __half2float(p45.x);
    }
    for (int off = 32; off; off >>= 1) {
        a0 += __shfl_down(a0, off); a1 += __shfl_down(a1, off); a2 += __shfl_down(a2, off);
        a3 += __shfl_down(a3, off); a4 += __shfl_down(a4, off);
    }
    if (lane == 0) {
        float di = dinv[node];
        const __half* xn = &xp[node * 8];
        float* pp = &p[node * IN_F];
        pp[0] = di * (a0 + __half2float(xn[0]));
        pp[1] = di * (a1 + __half2float(xn[1]));
        pp[2] = di * (a2 + __half2float(xn[2]));
        pp[3] = di * (a3 + __half2float(xn[3]));
        pp[4] = di * (a4 + __half2float(xn[4]));
    }
}

// ---------- fused h1 = relu(p@W1+b1); g' = (h1@W2)*dinv -> biased-u8/row + scale ----------
__global__ void k_h1g(const float* p, const float* W1, const float* b1,
                      const float* W2, const float* dinv,
                      unsigned char* g8u, float* rs) {
    __shared__ float W1s[IN_F * HID];
    __shared__ float W2s[HID * HID];
    __shared__ float b1s[HID];
    int t = threadIdx.x;
    for (int k = t; k < IN_F * HID; k += 256) W1s[k] = W1[k];
    for (int k = t; k < HID * HID; k += 256) W2s[k] = W2[k];
    if (t < HID) b1s[t] = b1[t];
    __syncthreads();
    int lane = t & 63;
    int wid = blockIdx.x * 4 + (t >> 6);
    int nw = gridDim.x * 4;
    for (int node = wid; node < N_NODES; node += nw) {
        const float* pp = &p[node * IN_F];
        float pv0 = pp[0], pv1 = pp[1], pv2 = pp[2], pv3 = pp[3], pv4 = pp[4];
        float h = b1s[lane] + pv0 * W1s[lane] + pv1 * W1s[64 + lane] + pv2 * W1s[128 + lane]
                + pv3 * W1s[192 + lane] + pv4 * W1s[256 + lane];
        h = fmaxf(h, 0.f);
        float acc = 0.f;
#pragma unroll
        for (int f = 0; f < HID; ++f) {
            float hf = __int_as_float(__builtin_amdgcn_readlane(__float_as_int(h), f));
            acc += hf * W2s[f * HID + lane];
        }
        float gv = acc * dinv[node];                 // g' value
        float am = fabsf(gv);
        for (int off = 32; off; off >>= 1) am = fmaxf(am, __shfl_xor(am, off));
        float inv = (am > 0.f) ? 127.0f / am : 0.f;
        g8u[node * HID + lane] = (unsigned char)(__float2int_rn(gv * inv) + 128);
        if (lane == 0) rs[node] = (am > 0.f) ? am * (1.0f / 127.0f) : 0.f;
    }
}

// ---------- layer-2: dword gather (4 feats/lane, 4 edges/wave) + bias/relu/pool ----------
#define EDGE4_BODY(UU)                                                         \
    {                                                                          \
        int u_ = (UU);                                                         \
        float w_ = __half2float(__ushort_as_half((unsigned short)((unsigned)u_ >> 16))); \
        float wwv_ = w_ * rs[u_ & 0xFFFF];                                     \
        unsigned dw_ = *(const unsigned*)&g8u[(u_ & 0xFFFF) * HID + fo];       \
        a0 += wwv_ * (float)(dw_ & 0xFF);                                      \
        a1 += wwv_ * (float)((dw_ >> 8) & 0xFF);                               \
        a2 += wwv_ * (float)((dw_ >> 16) & 0xFF);                              \
        a3 += wwv_ * (float)(dw_ >> 24);                                       \
        sww += wwv_;                                                           \
    }

__global__ __launch_bounds__(256, 8) void k_h2g(const int* rp2, const int* rp2e,
                      const int* pk, const float* dinv, const unsigned char* g8u,
                      const float* rs, const float* b2, const int* batch, float* pool) {
    int t = threadIdx.x, lane = t & 63;
    int grp = lane >> 4;                 // edge sub-group 0..3
    int fo = (lane & 15) << 2;           // feature offset 0..60
    int wid = blockIdx.x * 4 + (t >> 6);
    int n0 = (int)(((long long)wid * N_NODES) / NWAVE);
    int n1 = (int)(((long long)(wid + 1) * N_NODES) / NWAVE);
    if (n0 >= n1) return;
    float4 bj = *reinterpret_cast<const float4*>(&b2[fo]);
    float p0 = 0.f, p1 = 0.f, p2 = 0.f, p3 = 0.f;
    int cur = batch[n0];
    for (int node = n0; node < n1; ++node) {
        // self-loop, quarter-weighted (x4 across groups = exact)
        unsigned dws = *(const unsigned*)&g8u[node * HID + fo];
        float wq4 = 0.25f * rs[node];
        float a0 = wq4 * (float)(dws & 0xFF);
        float a1 = wq4 * (float)((dws >> 8) & 0xFF);
        float a2 = wq4 * (float)((dws >> 16) & 0xFF);
        float a3 = wq4 * (float)(dws >> 24);
        float sww = wq4;
        for (int k0 = rp2[node], e1 = rp2e[node]; k0 < e1; k0 += 64) {
            int kk = k0 + lane;
            int ev = (kk < e1) ? pk[kk] : 0;          // pad: src=0, w=+0.0
            int m = e1 - k0; if (m > 64) m = 64;
            if (m == 64) {
#pragma unroll
                for (int q = 0; q < 16; ++q) EDGE4_BODY(__shfl(ev, (q << 2) | grp))
            } else {
                int ng = (m + 3) >> 2;
                for (int q = 0; q < ng; ++q) EDGE4_BODY(__shfl(ev, (q << 2) | grp))
            }
        }
        // reduce across the 4 groups
#pragma unroll
        for (int off = 16; off <= 32; off <<= 1) {
            a0 += __shfl_xor(a0, off); a1 += __shfl_xor(a1, off);
            a2 += __shfl_xor(a2, off); a3 += __shfl_xor(a3, off);
            sww += __shfl_xor(sww, off);
        }
        float di = dinv[node];
        float corr = 128.0f * sww;
        float h0 = fmaxf(di * (a0 - corr) + bj.x, 0.f);
        float h1 = fmaxf(di * (a1 - corr) + bj.y, 0.f);
        float h2 = fmaxf(di * (a2 - corr) + bj.z, 0.f);
        float h3 = fmaxf(di * (a3 - corr) + bj.w, 0.f);
        int bb = batch[node];
        if (bb != cur) {
            if (lane < 16) {
                float* pb = &pool[cur * HID + fo];
                atomicAdd(pb + 0, p0); atomicAdd(pb + 1, p1);
                atomicAdd(pb + 2, p2); atomicAdd(pb + 3, p3);
            }
            cur = bb;
            p0 = p1 = p2 = p3 = 0.f;
        }
        p0 += h0; p1 += h1; p2 += h2; p3 += h3;
    }
    if (lane < 16) {
        float* pb = &pool[cur * HID + fo];
        atomicAdd(pb + 0, p0); atomicAdd(pb + 1, p1);
        atomicAdd(pb + 2, p2); atomicAdd(pb + 3, p3);
    }
}

__device__ int lowb(const int* a, int n, int v) {
    int lo = 0, hi = n;
    while (lo < hi) { int m = (lo + hi) >> 1; if (a[m] < v) lo = m + 1; else hi = m; }
    return lo;
}

__global__ void k_out(const float* pool, const int* batch, const float* Wo,
                      const float* bo, float* out) {
    int t = blockIdx.x * blockDim.x + threadIdx.x;
    if (t < N_GRAPHS * OUT_F) {
        int gi = t / OUT_F, k = t % OUT_F;
        int c = lowb(batch, N_NODES, gi + 1) - lowb(batch, N_NODES, gi);
        float cf = fmaxf((float)c, 1.0f);
        float acc = bo[k];
        for (int f = 0; f < HID; ++f)
            acc += (pool[gi * HID + f] / cf) * Wo[f * OUT_F + k];
        out[t] = acc;
    }
}

extern "C" void kernel_launch(void* const* d_in, const int* in_sizes, int n_in,
                              void* d_out, int out_size, void* d_ws, size_t ws_size,
                              hipStream_t stream) {
    const float* x   = (const float*)d_in[0];
    const int*   ei  = (const int*)d_in[1];
    const float* ea  = (const float*)d_in[2];
    const int*   bat = (const int*)d_in[3];
    const float* W1  = (const float*)d_in[4];
    const float* b1  = (const float*)d_in[5];
    const float* W2  = (const float*)d_in[6];
    const float* b2  = (const float*)d_in[7];
    const float* Wo  = (const float*)d_in[8];
    const float* bo  = (const float*)d_in[9];
    float* out = (float*)d_out;

    const int* src = ei;
    const int* dst = ei + N_EDGES;

    // workspace layout (float units) — total 4,654,832 floats = 18.6 MB
    float* ws = (float*)d_ws;
    int*   rpB   = (int*)ws;                         // 1564 (pad 1568)
    int*   rp2   = (int*)(ws + 1568);                // 50000 (pad 50016)
    int*   rp2e  = (int*)(ws + 51584);               // 50000 (pad 50016)
    float* dinv  = ws + 101600;                      // 50000 (pad 50016)
    float* rs    = ws + 151616;                      // 50000 (pad 50016)
    float* pool  = ws + 201632;                      // 3200
    int*   total = (int*)(ws + 201632);              // 1563, overlays pool, dead after bscanB
    unsigned short* cw = (unsigned short*)(ws + 204832);  // 390750 u16, dead after k_bucket
    float* p     = ws + 204832;                      // 250000, overlays cw, written after
    int*   bkt   = (int*)(ws + 454832);              // 3.2M ints (4B packed edges)
    unsigned char* g8u = (unsigned char*)(ws + 3654832);  // 3.2MB = 800000 floats
    __half* xp   = (__half*)(ws + 4454832);          // 400000 halves = 200000 floats

    k_bhist <<<NB1, 1024, 0, stream>>>(dst, cw);
    k_bscanA<<<NBKT, 256, 0, stream>>>(cw, total);
    k_bscanB<<<1, 256, 0, stream>>>(total, rpB);
    hipMemsetAsync(pool, 0, N_GRAPHS * HID * sizeof(float), stream);  // after bscanB (total overlays pool)
    k_bucket<<<NB1, 1024, 0, stream>>>(src, dst, ea, cw, rpB, bkt);
    k_bsort <<<NBKT, 256, 0, stream>>>(rpB, bkt, rp2, rp2e, dinv);
    k_xprep <<<(N_NODES + 255) / 256, 256, 0, stream>>>(x, dinv, xp);
    k_p     <<<(N_NODES + 3) / 4, 256, 0, stream>>>(rp2, rp2e, bkt, xp, dinv, p);
    k_h1g   <<<1024, 256, 0, stream>>>(p, W1, b1, W2, dinv, g8u, rs);
    k_h2g   <<<NWAVE / 4, 256, 0, stream>>>(rp2, rp2e, bkt, dinv, g8u, rs, b2, bat, pool);
    k_out   <<<1, 128, 0, stream>>>(pool, bat, Wo, bo, out);
}